// Round 4
// baseline (328.531 us; speedup 1.0000x reference)
//
#include <hip/hip_runtime.h>
#include <math.h>

typedef __attribute__((ext_vector_type(8))) short short8;
typedef __attribute__((ext_vector_type(4))) float f32x4;

#define CIN 66
#define BN_EPS 1e-5f

// haloed up-plane: 130 rows x 136 cols of u16
// (1-row top/bottom halo, 4-col left halo, interior cols [4,132), right pad)
// row pitch 272 B (8B-aligned); interior col w -> storage col w+4 (8B-aligned uint2 stores)
#define PLROW 136
#define PLN   17680            /* 130*136 u16 per (b,oc) plane; 512 planes = 18.1 MB */

// ---- ws layout ----
// u16   [0, 512*PLN)        up (bf16) haloed planes           (ends at float 4,526,080)
// float [CO_F, +1048576)    coord-channel output field co[64][16384] (fp32)
// u16   [BSQ_U16, +BSQ_CNT) squeeze-B fragment stream
// u16   [BF_U16, +BF_CNT)   fused-B fragment stream, PADDED K'=640 (20 ks * 4 nt)
//       k' = chunk*160 + wvv*40 + s ; s<36 -> real k = chunk*144 + wvv*36 + s ; else 0
// float [SC_F,+594) scale, [SH_F,+594) shift
// float [GW2_F,+594)  gw * log2(e)/9   (softmax exponent prefold)
// float [GF2_F,+5346) gf * bn_scale    (conv weight prefold)
#define CO_F     ((size_t)4587520)
#define BSQ_U16  ((size_t)16777216)
#define BSQ_CNT  32768                /* 8 kc * 8 nt * 64 * 8 */
#define BF_U16   (BSQ_U16 + BSQ_CNT)
#define BF_CNT   40960                /* 20 ks * 4 nt * 64 * 8 */
#define SC_F     ((size_t)8425472)
#define SH_F     (SC_F + 594)
#define GW2_F    (SH_F + 594)
#define GF2_F    (GW2_F + 594)

// precise RNE (prep only)
static __device__ __forceinline__ unsigned short f2bf(float f) {
    unsigned u = __float_as_uint(f);
    u += 0x7fffu + ((u >> 16) & 1u);
    return (unsigned short)(u >> 16);
}
// fast pack: round-half-up + v_perm_b32
static __device__ __forceinline__ unsigned pack2(float lo, float hi) {
    return __builtin_amdgcn_perm(__float_as_uint(hi) + 0x8000u,
                                 __float_as_uint(lo) + 0x8000u, 0x07060302u);
}

// ------------------------------------------------------------------
// prep: BN fold + B streams + halo zero + coord field + weight prefolds
// grid MUST be 256 blocks x 256 threads (co-field uses all 65536 threads)
// ------------------------------------------------------------------
__global__ void prep_kernel(const float* __restrict__ w_squeeze,
                            const float* __restrict__ gamma,
                            const float* __restrict__ beta,
                            const float* __restrict__ mean,
                            const float* __restrict__ var,
                            const float* __restrict__ w_gw,
                            const float* __restrict__ w_gf,
                            const float* __restrict__ w_conv,
                            float* __restrict__ ws)
{
    unsigned short* wsu = (unsigned short*)ws;
    const int tid = blockIdx.x * blockDim.x + threadIdx.x;
    const int nth = gridDim.x * blockDim.x;

    for (int idx = tid; idx < BSQ_CNT; idx += nth) {
        int j = idx & 7, lane = (idx >> 3) & 63, r = idx >> 9;
        int nt = r & 7, kc = r >> 3;
        int k = kc * 32 + ((lane >> 4) << 3) + j;
        int n = nt * 16 + (lane & 15);
        wsu[BSQ_U16 + idx] = f2bf(w_squeeze[n * 256 + k]);
    }
    // fused B stream: padded K' = 640 (4 chunks x 4 waves x 40, 36 real + 4 pad)
    for (int idx = tid; idx < BF_CNT; idx += nth) {
        int j = idx & 7, lane = (idx >> 3) & 63, r = idx >> 9;
        int nt = r & 3, ks = r >> 2;                 // ks 0..19
        int kp = ks * 32 + ((lane >> 4) << 3) + j;   // k' 0..639
        int chunk = kp / 160, rem = kp - chunk * 160;
        int wvv = rem / 40, s = rem - wvv * 40;
        int n = nt * 16 + (lane & 15);
        float v = 0.f;
        if (s < 36) v = w_conv[n * 594 + chunk * 144 + wvv * 36 + s];
        wsu[BF_U16 + idx] = f2bf(v);
    }
    for (int i = tid; i < CIN * 9; i += nth) {
        float sc = gamma[i] / sqrtf(var[i] + BN_EPS);
        ws[SC_F + i] = sc;
        ws[SH_F + i] = beta[i] - mean[i] * sc;
    }
    // softmax-exponent prefold: exp(p*gw) = exp2(sum * gw * log2e/9)
    for (int i = tid; i < CIN * 9; i += nth)
        ws[GW2_F + i] = w_gw[i] * 0.16029944573f;
    // conv-weight prefold: gf2 = gf * bn_scale  (accumulate from shift)
    for (int i = tid; i < CIN * 81; i += nth) {
        int cj = i / 9;   // = ch*9 + j
        float sc = gamma[cj] * rsqrtf(var[cj] + BN_EPS);
        ws[GF2_F + i] = w_gf[i] * sc;
    }
    // zero halo of all 512 planes: 648 u32 per plane
    for (int idx = tid; idx < 512 * 648; idx += nth) {
        int plane = idx / 648, r = idx - plane * 648;
        unsigned* pb = (unsigned*)(wsu + (size_t)plane * PLN);
        if (r < 68)       pb[r] = 0u;
        else if (r < 136) pb[8772 + (r - 68)] = 0u;
        else {
            int rr = (r - 136) >> 2, k = (r - 136) & 3;
            pb[(rr + 1) * 68 + (k < 2 ? k : 64 + k)] = 0u;
        }
    }
    // coordinate-channel contribution field (input-independent, exact fp32)
    if (tid < 65536) {
        const int pix = tid & 16383;
        const int g   = tid >> 14;
        const int h = pix >> 7, w = pix & 127;
        float fsA[9], fsB[9];
#pragma unroll
        for (int c = 0; c < 2; ++c) {
            const int cu = 64 + c;
            float n[9];
#pragma unroll
            for (int dy = 0; dy < 3; ++dy)
#pragma unroll
                for (int dx = 0; dx < 3; ++dx) {
                    const int gy = h - 1 + dy, gx = w - 1 + dx;
                    const bool ok = ((unsigned)gy < 128u) & ((unsigned)gx < 128u);
                    const float v = (c == 0) ? (gx * (2.f / 127.f) - 1.f)
                                             : (gy * (2.f / 127.f) - 1.f);
                    n[dy * 3 + dx] = ok ? v : 0.f;
                }
            const float p = (n[0]+n[1]+n[2]+n[3]+n[4]+n[5]+n[6]+n[7]+n[8]) * (1.f/9.f);
            const float* gw = w_gw + cu * 9;
            const float* gf = w_gf + cu * 81;
            float e[9], se = 0.f;
#pragma unroll
            for (int j = 0; j < 9; ++j) { e[j] = __expf(p * gw[j]); se += e[j]; }
            const float sinv = 1.f / se;
            float* fs = c ? fsB : fsA;
#pragma unroll
            for (int j = 0; j < 9; ++j) {
                float cv = 0.f;
#pragma unroll
                for (int i = 0; i < 9; ++i) cv = fmaf(n[i], gf[j * 9 + i], cv);
                const float sc = gamma[cu * 9 + j] / sqrtf(var[cu * 9 + j] + BN_EPS);
                const float sh = beta[cu * 9 + j] - mean[cu * 9 + j] * sc;
                const float f = fmaf(cv, sc, sh);
                fs[j] = fmaxf(f, 0.f) * (e[j] * sinv);
            }
        }
#pragma unroll 1
        for (int oc = g * 16; oc < g * 16 + 16; ++oc) {
            const float* wc = w_conv + oc * 594;
            float s = 0.f;
#pragma unroll
            for (int j = 0; j < 9; ++j)
                s = fmaf(fsA[j], wc[576 + j], fmaf(fsB[j], wc[585 + j], s));
            ws[CO_F + (size_t)oc * 16384 + pix] = s;
        }
    }
}

// ------------------------------------------------------------------
// squeeze: space-to-depth + 1x1 conv as bf16 MFMA GEMM
// v4: two-phase A-load/pack (v[8] reused per gy) -> peak VGPR ~60 -> (256,5)
//     matches the 5-block LDS limit (32KB). sched_barrier pins the phases.
// ------------------------------------------------------------------
__global__ __launch_bounds__(256, 5) void squeeze_mfma(
    const float* __restrict__ x,
    float* __restrict__ wsp,
    float* __restrict__ out)
{
    __shared__ uint4 As[32 * 64];   // 32768 B -> 5 blocks/CU

    const int bx  = blockIdx.x;
    const int b   = bx & 7;         // batch -> XCD affinity
    const int pos = bx >> 3;        // 0..255
    const int h   = pos >> 1;
    const int w0  = (pos & 1) * 64;
    const int tid  = threadIdx.x;
    const int lane = tid & 63;
    const int wv   = tid >> 6;
    const int oct = tid >> 5;       // 0..7
    const int pp  = tid & 31;       // pixel pair

    // ---- A load+pack in two phases (gy=0 then gy=1), 8 float4 live each ----
#pragma unroll
    for (int gy = 0; gy < 2; ++gy) {
        float4 v[8];
#pragma unroll
        for (int i = 0; i < 8; ++i)
            v[i] = *(const float4*)(x +
                (size_t)(b * 64 + oct * 8 + i) * 65536 +
                (2 * h + gy) * 256 + 2 * w0 + 4 * pp);
#pragma unroll
        for (int gx = 0; gx < 2; ++gx)
#pragma unroll
            for (int p = 0; p < 2; ++p) {
                const int comp = p * 2 + gx;
                uint4 u;
                u.x = pack2(((const float*)&v[0])[comp], ((const float*)&v[1])[comp]);
                u.y = pack2(((const float*)&v[2])[comp], ((const float*)&v[3])[comp]);
                u.z = pack2(((const float*)&v[4])[comp], ((const float*)&v[5])[comp]);
                u.w = pack2(((const float*)&v[6])[comp], ((const float*)&v[7])[comp]);
                As[((gy + 2 * gx) * 8 + oct) * 64 + 2 * pp + p] = u;
            }
        __builtin_amdgcn_sched_barrier(0);   // keep phases separate (VGPR cap)
    }

    // ---- first B fragments in flight under the barrier ----
    const unsigned short* bsq = (const unsigned short*)wsp + BSQ_U16;
    short8 b0 = *(const short8*)(bsq + (size_t)((2 * wv + 0) * 64 + lane) * 8);
    short8 b1 = *(const short8*)(bsq + (size_t)((2 * wv + 1) * 64 + lane) * 8);

    __syncthreads();

    // ---- MFMA: software-pipelined B loads ----
    const int q = lane >> 4, m = lane & 15;
    f32x4 acc[4][2];
#pragma unroll
    for (int mt = 0; mt < 4; ++mt)
#pragma unroll
        for (int j = 0; j < 2; ++j) acc[mt][j] = (f32x4){0.f, 0.f, 0.f, 0.f};

#pragma unroll
    for (int ks = 0; ks < 8; ++ks) {
        short8 nb0, nb1;
        if (ks < 7) {
            nb0 = *(const short8*)(bsq + (size_t)(((ks + 1) * 8 + 2 * wv + 0) * 64 + lane) * 8);
            nb1 = *(const short8*)(bsq + (size_t)(((ks + 1) * 8 + 2 * wv + 1) * 64 + lane) * 8);
        }
#pragma unroll
        for (int mt = 0; mt < 4; ++mt) {
            short8 a = *(const short8*)&As[(ks * 4 + q) * 64 + mt * 16 + m];
            acc[mt][0] = __builtin_amdgcn_mfma_f32_16x16x32_bf16(a, b0, acc[mt][0], 0, 0, 0);
            acc[mt][1] = __builtin_amdgcn_mfma_f32_16x16x32_bf16(a, b1, acc[mt][1], 0, 0, 0);
        }
        if (ks < 7) { b0 = nb0; b1 = nb1; }
    }

    // ---- epilogue: waves 0,1 -> up (bf16, haloed); waves 2,3 -> out (fp32) ----
    if (wv < 2) {
        unsigned short* upw = (unsigned short*)wsp;
#pragma unroll
        for (int j = 0; j < 2; ++j) {
            const int oc = (2 * wv + j) * 16 + m;
#pragma unroll
            for (int mt = 0; mt < 4; ++mt) {
                uint2 st;
                st.x = pack2(acc[mt][j][0], acc[mt][j][1]);
                st.y = pack2(acc[mt][j][2], acc[mt][j][3]);
                *(uint2*)(upw + (size_t)(b * 64 + oc) * PLN + (size_t)(h + 1) * PLROW
                          + (w0 + mt * 16 + q * 4 + 4)) = st;
            }
        }
    } else {
#pragma unroll
        for (int j = 0; j < 2; ++j) {
            const int oc = (2 * wv + j) * 16 + m;
            const int lc = oc - 64;
            const int ch = (lc & 1) ? (96 + ((lc - 1) >> 1)) : (32 + (lc >> 1));
#pragma unroll
            for (int mt = 0; mt < 4; ++mt) {
                float4 st = {acc[mt][j][0], acc[mt][j][1], acc[mt][j][2], acc[mt][j][3]};
                *(float4*)(out + ((size_t)(b * 128 + ch) * 128 + h) * 128
                           + (w0 + mt * 16 + q * 4)) = st;
            }
        }
    }
}

// ------------------------------------------------------------------
// fused helpers (v4: prefolded weights, 4-channel strips, pinned prefetch)
// ------------------------------------------------------------------
__device__ __forceinline__ void fs_from_n2(
    int cu, const float n[9],
    const float* __restrict__ gw2, const float* __restrict__ gf2,
    const float* __restrict__ shp, float fs[9])
{
    const float s = ((n[0] + n[1]) + (n[2] + n[3])) + ((n[4] + n[5]) + (n[6] + n[7])) + n[8];
    const float* gw = gw2 + cu * 9;
    const float* gf = gf2 + cu * 81;
    const float* sh = shp + cu * 9;
    float e[9], se = 0.f;
#pragma unroll
    for (int j = 0; j < 9; ++j) { e[j] = __builtin_amdgcn_exp2f(s * gw[j]); se += e[j]; }
    const float sinv = __builtin_amdgcn_rcpf(se);
#pragma unroll
    for (int j = 0; j < 9; ++j) {
        float cv = sh[j];
#pragma unroll
        for (int i = 0; i < 9; ++i) cv = fmaf(n[i], gf[j * 9 + i], cv);
        fs[j] = fmaxf(cv, 0.f) * (e[j] * sinv);
    }
}

__device__ __forceinline__ void pack_into(unsigned* pk, int ci, const float fs[9], float& carry)
{
    const int off = 9 * ci;
    if ((ci & 1) == 0) {
#pragma unroll
        for (int t = 0; t < 4; ++t) pk[off / 2 + t] = pack2(fs[2 * t], fs[2 * t + 1]);
        carry = fs[8];
    } else {
        pk[(off - 1) / 2] = pack2(carry, fs[0]);
#pragma unroll
        for (int t = 0; t < 4; ++t) pk[(off + 1) / 2 + t] = pack2(fs[1 + 2 * t], fs[2 + 2 * t]);
    }
}

// 12 row-loads (4 ch x 3 rows) issued up front; sched_barrier pins them
// so the scheduler cannot sink them past the following MFMA phase.
__device__ __forceinline__ void chunk_loads4(
    int cbase, int lane, int h0, int w0,
    const unsigned short* __restrict__ upb, uint2 vr[4][3])
{
    const int px = lane & 7, py = lane >> 3;
    const size_t rowoff = (size_t)(h0 + py) * PLROW + (size_t)((w0 + px + 3) & ~1);
#pragma unroll
    for (int ci = 0; ci < 4; ++ci) {
        const int cu = __builtin_amdgcn_readfirstlane(cbase + ci);
        const unsigned short* cb = upb + (size_t)cu * PLN + rowoff;
#pragma unroll
        for (int dy = 0; dy < 3; ++dy)
            vr[ci][dy] = *(const uint2*)(cb + dy * PLROW);
    }
    __builtin_amdgcn_sched_barrier(0);   // loads stay issued HERE
}

// 4 channels -> pk[0..17] bf16-packed, pk[18..19] zero pad
__device__ __forceinline__ void chunk_compute4(
    int cbase, int lane, const uint2 vr[4][3],
    const float* __restrict__ gw2, const float* __restrict__ gf2,
    const float* __restrict__ shp, unsigned pk[20])
{
    const unsigned shf = (lane & 1) ? 0u : 16u;
    float carry = 0.f;
#pragma unroll
    for (int ci = 0; ci < 4; ++ci) {
        const int cu = __builtin_amdgcn_readfirstlane(cbase + ci);
        float n[9];
#pragma unroll
        for (int dy = 0; dy < 3; ++dy) {
            const uint2 vv = vr[ci][dy];
            unsigned long long t = (((unsigned long long)vv.y) << 32) | vv.x;
            t >>= shf;
            n[dy * 3 + 0] = __uint_as_float((unsigned)t << 16);
            n[dy * 3 + 1] = __uint_as_float((unsigned)t & 0xffff0000u);
            n[dy * 3 + 2] = __uint_as_float((unsigned)(t >> 32) << 16);
        }
        float fs[9];
        fs_from_n2(cu, n, gw2, gf2, shp, fs);
        pack_into(pk, ci, fs, carry);
    }
    pk[18] = 0u; pk[19] = 0u;
}

// one padded chunk: 5 k-steps
__device__ __forceinline__ void do_mfma5(
    int bbase, const uint4* As, const unsigned short* __restrict__ bfw,
    int wv, int lane, f32x4 acc[2][2])
{
    const int q = lane >> 4, m = lane & 15;
    const int ntb = (wv >> 1) * 2;
    const int pt0 = (wv & 1) * 2;
#pragma unroll
    for (int ks = 0; ks < 5; ++ks) {
        short8 b0 = *(const short8*)(bfw + (size_t)(((bbase + ks) * 4 + ntb + 0) * 64 + lane) * 8);
        short8 b1 = *(const short8*)(bfw + (size_t)(((bbase + ks) * 4 + ntb + 1) * 64 + lane) * 8);
#pragma unroll
        for (int mt = 0; mt < 2; ++mt) {
            short8 a = *(const short8*)&As[(ks * 4 + q) * 64 + (pt0 + mt) * 16 + m];
            acc[mt][0] = __builtin_amdgcn_mfma_f32_16x16x32_bf16(a, b0, acc[mt][0], 0, 0, 0);
            acc[mt][1] = __builtin_amdgcn_mfma_f32_16x16x32_bf16(a, b1, acc[mt][1], 0, 0, 0);
        }
    }
}

// ------------------------------------------------------------------
// fused v4: 4 padded chunks (K'=640), 20-row LDS (20480 B),
// (256,7) -> 7 blocks/CU, pinned load prefetch
// ------------------------------------------------------------------
__global__ __launch_bounds__(256, 7) void fused_mfma(
    const float* __restrict__ wsp,
    const float* __restrict__ b_conv,
    float* __restrict__ out)
{
    __shared__ uint4 As[20 * 64];   // 20480 B

    const int bx = blockIdx.x;
    const int b  = bx & 7;          // batch -> XCD affinity
    const int t  = bx >> 3;
    const int w0 = (t & 15) * 8;
    const int h0 = ((t >> 4) & 15) * 8;
    const int tid = threadIdx.x, lane = tid & 63, wv = tid >> 6;

    const unsigned short* upb = (const unsigned short*)wsp + (size_t)b * 64 * PLN;
    const float* gw2 = wsp + GW2_F;
    const float* gf2 = wsp + GF2_F;
    const float* shp = wsp + SH_F;
    const unsigned short* bfw = (const unsigned short*)wsp + BF_U16;

    f32x4 acc[2][2];
#pragma unroll
    for (int mt = 0; mt < 2; ++mt)
#pragma unroll
        for (int j = 0; j < 2; ++j) acc[mt][j] = (f32x4){0.f, 0.f, 0.f, 0.f};

    uint2 vr[4][3];
    unsigned pk[20];

    // prologue: chunk 0 (channels wv*4 .. wv*4+3)
    chunk_loads4(wv * 4, lane, h0, w0, upb, vr);
    chunk_compute4(wv * 4, lane, vr, gw2, gf2, shp, pk);
#pragma unroll
    for (int kb = 0; kb < 5; ++kb)
        As[(5 * wv + kb) * 64 + lane] =
            (uint4){pk[4 * kb], pk[4 * kb + 1], pk[4 * kb + 2], pk[4 * kb + 3]};
    __syncthreads();

#pragma unroll
    for (int c = 0; c < 4; ++c) {
        if (c < 3) chunk_loads4((c + 1) * 16 + wv * 4, lane, h0, w0, upb, vr);
        do_mfma5(c * 5, As, bfw, wv, lane, acc);
        if (c < 3) {
            chunk_compute4((c + 1) * 16 + wv * 4, lane, vr, gw2, gf2, shp, pk);
            __syncthreads();   // all waves done reading As for chunk c
#pragma unroll
            for (int kb = 0; kb < 5; ++kb)
                As[(5 * wv + kb) * 64 + lane] =
                    (uint4){pk[4 * kb], pk[4 * kb + 1], pk[4 * kb + 2], pk[4 * kb + 3]};
            __syncthreads();   // writes visible
        }
    }

    // ================= epilogue: + bias + coord field, float4 stores =================
    const int q = lane >> 4, m = lane & 15;
    const int ntb = (wv >> 1) * 2, pt0 = (wv & 1) * 2;
    const float* co = wsp + CO_F;
#pragma unroll
    for (int mt = 0; mt < 2; ++mt)
#pragma unroll
        for (int j = 0; j < 2; ++j) {
            const int oc = (ntb + j) * 16 + m;
            const int ch = (oc & 1) ? (64 + (oc >> 1)) : (oc >> 1);
            const int row = h0 + (pt0 + mt) * 2 + (q >> 1);
            const int col = w0 + (q & 1) * 4;
            const size_t pix = (size_t)row * 128 + col;
            const float4 cv = *(const float4*)(co + (size_t)oc * 16384 + pix);
            const float bias = b_conv[oc];
            float4 st = { acc[mt][j][0] + bias + cv.x,
                          acc[mt][j][1] + bias + cv.y,
                          acc[mt][j][2] + bias + cv.z,
                          acc[mt][j][3] + bias + cv.w };
            *(float4*)(out + (size_t)(b * 128 + ch) * 16384 + pix) = st;
        }
}

// ------------------------------------------------------------------
extern "C" void kernel_launch(void* const* d_in, const int* in_sizes, int n_in,
                              void* d_out, int out_size, void* d_ws, size_t ws_size,
                              hipStream_t stream)
{
    const float* x         = (const float*)d_in[0];
    const float* w_squeeze = (const float*)d_in[1];
    const float* w_gw      = (const float*)d_in[2];
    const float* w_gf      = (const float*)d_in[3];
    const float* gamma     = (const float*)d_in[4];
    const float* beta      = (const float*)d_in[5];
    const float* mean      = (const float*)d_in[6];
    const float* var       = (const float*)d_in[7];
    const float* w_conv    = (const float*)d_in[8];
    const float* b_conv    = (const float*)d_in[9];
    float* out = (float*)d_out;
    float* ws  = (float*)d_ws;

    prep_kernel<<<256, 256, 0, stream>>>(w_squeeze, gamma, beta, mean, var,
                                         w_gw, w_gf, w_conv, ws);
    squeeze_mfma<<<2048, 256, 0, stream>>>(x, ws, out);
    fused_mfma<<<2048, 256, 0, stream>>>(ws, b_conv, out);
}

// Round 5
// 319.099 us; speedup vs baseline: 1.0296x; 1.0296x over previous
//
#include <hip/hip_runtime.h>
#include <math.h>

typedef __attribute__((ext_vector_type(8))) short short8;
typedef __attribute__((ext_vector_type(4))) float f32x4;

#define CIN 66
#define BN_EPS 1e-5f

// haloed up-plane: 130 rows x 136 cols of u16
// (1-row top/bottom halo, 4-col left halo, interior cols [4,132), right pad)
// row pitch 272 B (8B-aligned); interior col w -> storage col w+4 (8B-aligned uint2 stores)
#define PLROW 136
#define PLN   17680            /* 130*136 u16 per (b,oc) plane; 512 planes = 18.1 MB */

// ---- ws layout ----
// u16   [0, 512*PLN)        up (bf16) haloed planes           (ends at float 4,526,080)
// float [CO_F, +1048576)    coord-channel output field co[64][16384] (fp32)
// u16   [BSQ_U16, +BSQ_CNT) squeeze-B fragment stream
// u16   [BF_U16, +BF_CNT)   fused-B fragment stream, PADDED K'=640 (20 ks * 4 nt)
//       k' = chunk*160 + wvv*40 + s ; s<36 -> real k = chunk*144 + wvv*36 + s ; else 0
// float [SC_F,+594) scale, [SH_F,+594) shift
// float [GW2_F,+594)  gw * log2(e)/9   (softmax exponent prefold)
// float [GF2_F,+5346) gf * bn_scale    (conv weight prefold)
#define CO_F     ((size_t)4587520)
#define BSQ_U16  ((size_t)16777216)
#define BSQ_CNT  32768                /* 8 kc * 8 nt * 64 * 8 */
#define BF_U16   (BSQ_U16 + BSQ_CNT)
#define BF_CNT   40960                /* 20 ks * 4 nt * 64 * 8 */
#define SC_F     ((size_t)8425472)
#define SH_F     (SC_F + 594)
#define GW2_F    (SH_F + 594)
#define GF2_F    (GW2_F + 594)

// precise RNE (prep only)
static __device__ __forceinline__ unsigned short f2bf(float f) {
    unsigned u = __float_as_uint(f);
    u += 0x7fffu + ((u >> 16) & 1u);
    return (unsigned short)(u >> 16);
}
// fast pack: round-half-up + v_perm_b32
static __device__ __forceinline__ unsigned pack2(float lo, float hi) {
    return __builtin_amdgcn_perm(__float_as_uint(hi) + 0x8000u,
                                 __float_as_uint(lo) + 0x8000u, 0x07060302u);
}

// ------------------------------------------------------------------
// prep: BN fold + B streams + halo zero + coord field + weight prefolds
// grid MUST be 256 blocks x 256 threads (co-field uses all 65536 threads)
// ------------------------------------------------------------------
__global__ void prep_kernel(const float* __restrict__ w_squeeze,
                            const float* __restrict__ gamma,
                            const float* __restrict__ beta,
                            const float* __restrict__ mean,
                            const float* __restrict__ var,
                            const float* __restrict__ w_gw,
                            const float* __restrict__ w_gf,
                            const float* __restrict__ w_conv,
                            float* __restrict__ ws)
{
    unsigned short* wsu = (unsigned short*)ws;
    const int tid = blockIdx.x * blockDim.x + threadIdx.x;
    const int nth = gridDim.x * blockDim.x;

    for (int idx = tid; idx < BSQ_CNT; idx += nth) {
        int j = idx & 7, lane = (idx >> 3) & 63, r = idx >> 9;
        int nt = r & 7, kc = r >> 3;
        int k = kc * 32 + ((lane >> 4) << 3) + j;
        int n = nt * 16 + (lane & 15);
        wsu[BSQ_U16 + idx] = f2bf(w_squeeze[n * 256 + k]);
    }
    // fused B stream: padded K' = 640 (4 chunks x 4 waves x 40, 36 real + 4 pad)
    for (int idx = tid; idx < BF_CNT; idx += nth) {
        int j = idx & 7, lane = (idx >> 3) & 63, r = idx >> 9;
        int nt = r & 3, ks = r >> 2;                 // ks 0..19
        int kp = ks * 32 + ((lane >> 4) << 3) + j;   // k' 0..639
        int chunk = kp / 160, rem = kp - chunk * 160;
        int wvv = rem / 40, s = rem - wvv * 40;
        int n = nt * 16 + (lane & 15);
        float v = 0.f;
        if (s < 36) v = w_conv[n * 594 + chunk * 144 + wvv * 36 + s];
        wsu[BF_U16 + idx] = f2bf(v);
    }
    for (int i = tid; i < CIN * 9; i += nth) {
        float sc = gamma[i] / sqrtf(var[i] + BN_EPS);
        ws[SC_F + i] = sc;
        ws[SH_F + i] = beta[i] - mean[i] * sc;
    }
    // softmax-exponent prefold: exp(p*gw) = exp2(sum * gw * log2e/9)
    for (int i = tid; i < CIN * 9; i += nth)
        ws[GW2_F + i] = w_gw[i] * 0.16029944573f;
    // conv-weight prefold: gf2 = gf * bn_scale  (accumulate from shift)
    for (int i = tid; i < CIN * 81; i += nth) {
        int cj = i / 9;   // = ch*9 + j
        float sc = gamma[cj] * rsqrtf(var[cj] + BN_EPS);
        ws[GF2_F + i] = w_gf[i] * sc;
    }
    // zero halo of all 512 planes: 648 u32 per plane
    for (int idx = tid; idx < 512 * 648; idx += nth) {
        int plane = idx / 648, r = idx - plane * 648;
        unsigned* pb = (unsigned*)(wsu + (size_t)plane * PLN);
        if (r < 68)       pb[r] = 0u;
        else if (r < 136) pb[8772 + (r - 68)] = 0u;
        else {
            int rr = (r - 136) >> 2, k = (r - 136) & 3;
            pb[(rr + 1) * 68 + (k < 2 ? k : 64 + k)] = 0u;
        }
    }
    // coordinate-channel contribution field (input-independent, exact fp32)
    if (tid < 65536) {
        const int pix = tid & 16383;
        const int g   = tid >> 14;
        const int h = pix >> 7, w = pix & 127;
        float fsA[9], fsB[9];
#pragma unroll
        for (int c = 0; c < 2; ++c) {
            const int cu = 64 + c;
            float n[9];
#pragma unroll
            for (int dy = 0; dy < 3; ++dy)
#pragma unroll
                for (int dx = 0; dx < 3; ++dx) {
                    const int gy = h - 1 + dy, gx = w - 1 + dx;
                    const bool ok = ((unsigned)gy < 128u) & ((unsigned)gx < 128u);
                    const float v = (c == 0) ? (gx * (2.f / 127.f) - 1.f)
                                             : (gy * (2.f / 127.f) - 1.f);
                    n[dy * 3 + dx] = ok ? v : 0.f;
                }
            const float p = (n[0]+n[1]+n[2]+n[3]+n[4]+n[5]+n[6]+n[7]+n[8]) * (1.f/9.f);
            const float* gw = w_gw + cu * 9;
            const float* gf = w_gf + cu * 81;
            float e[9], se = 0.f;
#pragma unroll
            for (int j = 0; j < 9; ++j) { e[j] = __expf(p * gw[j]); se += e[j]; }
            const float sinv = 1.f / se;
            float* fs = c ? fsB : fsA;
#pragma unroll
            for (int j = 0; j < 9; ++j) {
                float cv = 0.f;
#pragma unroll
                for (int i = 0; i < 9; ++i) cv = fmaf(n[i], gf[j * 9 + i], cv);
                const float sc = gamma[cu * 9 + j] / sqrtf(var[cu * 9 + j] + BN_EPS);
                const float sh = beta[cu * 9 + j] - mean[cu * 9 + j] * sc;
                const float f = fmaf(cv, sc, sh);
                fs[j] = fmaxf(f, 0.f) * (e[j] * sinv);
            }
        }
#pragma unroll 1
        for (int oc = g * 16; oc < g * 16 + 16; ++oc) {
            const float* wc = w_conv + oc * 594;
            float s = 0.f;
#pragma unroll
            for (int j = 0; j < 9; ++j)
                s = fmaf(fsA[j], wc[576 + j], fmaf(fsB[j], wc[585 + j], s));
            ws[CO_F + (size_t)oc * 16384 + pix] = s;
        }
    }
}

// ------------------------------------------------------------------
// squeeze v5: 32-px tile (As=16KB), 8 float4/thread all in flight,
// (256,7) -> 7 blocks/CU (87.5% occupancy cap). Wave roles, B-stream,
// epilogue identical to R3 (mt<2, w0 in 32-steps, 4096 blocks).
// ------------------------------------------------------------------
__global__ __launch_bounds__(256, 7) void squeeze_mfma(
    const float* __restrict__ x,
    float* __restrict__ wsp,
    float* __restrict__ out)
{
    __shared__ __align__(16) uint2 As2[32 * 32 * 2];   // 16384 B

    const int bx  = blockIdx.x;
    const int b   = bx & 7;         // batch -> XCD affinity
    const int pos = bx >> 3;        // 0..511
    const int h   = pos >> 2;
    const int w0  = (pos & 3) * 32;
    const int tid  = threadIdx.x;
    const int lane = tid & 63;
    const int wv   = tid >> 6;      // 0..3
    const int oct  = tid >> 5;      // 0..7 : channel group oct*8
    const int hf   = (tid >> 4) & 1;// half of the channel group
    const int pp   = tid & 15;      // pixel pair 0..15

    // ---- A loads: 8 float4, all issued up front ----
    float4 v[2][4];
#pragma unroll
    for (int gy = 0; gy < 2; ++gy)
#pragma unroll
        for (int i = 0; i < 4; ++i)
            v[gy][i] = *(const float4*)(x +
                (size_t)(b * 64 + oct * 8 + hf * 4 + i) * 65536 +
                (2 * h + gy) * 256 + 2 * w0 + 4 * pp);

    // ---- pack to fragment rows: row r=(gy+2*gx)*8+oct, pixel 2pp+p, half hf ----
#pragma unroll
    for (int gy = 0; gy < 2; ++gy)
#pragma unroll
        for (int gx = 0; gx < 2; ++gx)
#pragma unroll
            for (int p = 0; p < 2; ++p) {
                const int comp = p * 2 + gx;
                uint2 u;
                u.x = pack2(((const float*)&v[gy][0])[comp], ((const float*)&v[gy][1])[comp]);
                u.y = pack2(((const float*)&v[gy][2])[comp], ((const float*)&v[gy][3])[comp]);
                As2[(((gy + 2 * gx) * 8 + oct) * 32 + 2 * pp + p) * 2 + hf] = u;
            }

    // ---- first B fragments in flight under the barrier ----
    const unsigned short* bsq = (const unsigned short*)wsp + BSQ_U16;
    short8 b0 = *(const short8*)(bsq + (size_t)((2 * wv + 0) * 64 + lane) * 8);
    short8 b1 = *(const short8*)(bsq + (size_t)((2 * wv + 1) * 64 + lane) * 8);

    __syncthreads();

    // ---- MFMA: software-pipelined B loads ----
    const uint4* As4 = (const uint4*)As2;
    const int q = lane >> 4, m = lane & 15;
    f32x4 acc[2][2];
#pragma unroll
    for (int mt = 0; mt < 2; ++mt)
#pragma unroll
        for (int j = 0; j < 2; ++j) acc[mt][j] = (f32x4){0.f, 0.f, 0.f, 0.f};

#pragma unroll
    for (int ks = 0; ks < 8; ++ks) {
        short8 nb0, nb1;
        if (ks < 7) {
            nb0 = *(const short8*)(bsq + (size_t)(((ks + 1) * 8 + 2 * wv + 0) * 64 + lane) * 8);
            nb1 = *(const short8*)(bsq + (size_t)(((ks + 1) * 8 + 2 * wv + 1) * 64 + lane) * 8);
        }
#pragma unroll
        for (int mt = 0; mt < 2; ++mt) {
            short8 a = *(const short8*)&As4[(ks * 4 + q) * 32 + mt * 16 + m];
            acc[mt][0] = __builtin_amdgcn_mfma_f32_16x16x32_bf16(a, b0, acc[mt][0], 0, 0, 0);
            acc[mt][1] = __builtin_amdgcn_mfma_f32_16x16x32_bf16(a, b1, acc[mt][1], 0, 0, 0);
        }
        if (ks < 7) { b0 = nb0; b1 = nb1; }
    }

    // ---- epilogue: waves 0,1 -> up (bf16, haloed); waves 2,3 -> out (fp32) ----
    if (wv < 2) {
        unsigned short* upw = (unsigned short*)wsp;
#pragma unroll
        for (int j = 0; j < 2; ++j) {
            const int oc = (2 * wv + j) * 16 + m;
#pragma unroll
            for (int mt = 0; mt < 2; ++mt) {
                uint2 st;
                st.x = pack2(acc[mt][j][0], acc[mt][j][1]);
                st.y = pack2(acc[mt][j][2], acc[mt][j][3]);
                *(uint2*)(upw + (size_t)(b * 64 + oc) * PLN + (size_t)(h + 1) * PLROW
                          + (w0 + mt * 16 + q * 4 + 4)) = st;
            }
        }
    } else {
#pragma unroll
        for (int j = 0; j < 2; ++j) {
            const int oc = (2 * wv + j) * 16 + m;
            const int lc = oc - 64;
            const int ch = (lc & 1) ? (96 + ((lc - 1) >> 1)) : (32 + (lc >> 1));
#pragma unroll
            for (int mt = 0; mt < 2; ++mt) {
                float4 st = {acc[mt][j][0], acc[mt][j][1], acc[mt][j][2], acc[mt][j][3]};
                *(float4*)(out + ((size_t)(b * 128 + ch) * 128 + h) * 128
                           + (w0 + mt * 16 + q * 4)) = st;
            }
        }
    }
}

// ------------------------------------------------------------------
// fused helpers (R3 exact: prefolded weights, 4-channel strips)
// ------------------------------------------------------------------
__device__ __forceinline__ void fs_from_n2(
    int cu, const float n[9],
    const float* __restrict__ gw2, const float* __restrict__ gf2,
    const float* __restrict__ shp, float fs[9])
{
    const float s = ((n[0] + n[1]) + (n[2] + n[3])) + ((n[4] + n[5]) + (n[6] + n[7])) + n[8];
    const float* gw = gw2 + cu * 9;
    const float* gf = gf2 + cu * 81;
    const float* sh = shp + cu * 9;
    float e[9], se = 0.f;
#pragma unroll
    for (int j = 0; j < 9; ++j) { e[j] = __builtin_amdgcn_exp2f(s * gw[j]); se += e[j]; }
    const float sinv = __builtin_amdgcn_rcpf(se);
#pragma unroll
    for (int j = 0; j < 9; ++j) {
        float cv = sh[j];
#pragma unroll
        for (int i = 0; i < 9; ++i) cv = fmaf(n[i], gf[j * 9 + i], cv);
        fs[j] = fmaxf(cv, 0.f) * (e[j] * sinv);
    }
}

__device__ __forceinline__ void pack_into(unsigned* pk, int ci, const float fs[9], float& carry)
{
    const int off = 9 * ci;
    if ((ci & 1) == 0) {
#pragma unroll
        for (int t = 0; t < 4; ++t) pk[off / 2 + t] = pack2(fs[2 * t], fs[2 * t + 1]);
        carry = fs[8];
    } else {
        pk[(off - 1) / 2] = pack2(carry, fs[0]);
#pragma unroll
        for (int t = 0; t < 4; ++t) pk[(off + 1) / 2 + t] = pack2(fs[1 + 2 * t], fs[2 + 2 * t]);
    }
}

// 12 row-loads (4 ch x 3 rows) issued up front
__device__ __forceinline__ void chunk_loads4(
    int cbase, int lane, int h0, int w0,
    const unsigned short* __restrict__ upb, uint2 vr[4][3])
{
    const int px = lane & 7, py = lane >> 3;
    const size_t rowoff = (size_t)(h0 + py) * PLROW + (size_t)((w0 + px + 3) & ~1);
#pragma unroll
    for (int ci = 0; ci < 4; ++ci) {
        const int cu = __builtin_amdgcn_readfirstlane(cbase + ci);
        const unsigned short* cb = upb + (size_t)cu * PLN + rowoff;
#pragma unroll
        for (int dy = 0; dy < 3; ++dy)
            vr[ci][dy] = *(const uint2*)(cb + dy * PLROW);
    }
}

// 4 channels -> pk[0..17] bf16-packed, pk[18..19] zero pad
__device__ __forceinline__ void chunk_compute4(
    int cbase, int lane, const uint2 vr[4][3],
    const float* __restrict__ gw2, const float* __restrict__ gf2,
    const float* __restrict__ shp, unsigned pk[20])
{
    const unsigned shf = (lane & 1) ? 0u : 16u;
    float carry = 0.f;
#pragma unroll
    for (int ci = 0; ci < 4; ++ci) {
        const int cu = __builtin_amdgcn_readfirstlane(cbase + ci);
        float n[9];
#pragma unroll
        for (int dy = 0; dy < 3; ++dy) {
            const uint2 vv = vr[ci][dy];
            unsigned long long t = (((unsigned long long)vv.y) << 32) | vv.x;
            t >>= shf;
            n[dy * 3 + 0] = __uint_as_float((unsigned)t << 16);
            n[dy * 3 + 1] = __uint_as_float((unsigned)t & 0xffff0000u);
            n[dy * 3 + 2] = __uint_as_float((unsigned)(t >> 32) << 16);
        }
        float fs[9];
        fs_from_n2(cu, n, gw2, gf2, shp, fs);
        pack_into(pk, ci, fs, carry);
    }
    pk[18] = 0u; pk[19] = 0u;
}

// one padded chunk: 5 k-steps
__device__ __forceinline__ void do_mfma5(
    int bbase, const uint4* As, const unsigned short* __restrict__ bfw,
    int wv, int lane, f32x4 acc[2][2])
{
    const int q = lane >> 4, m = lane & 15;
    const int ntb = (wv >> 1) * 2;
    const int pt0 = (wv & 1) * 2;
#pragma unroll
    for (int ks = 0; ks < 5; ++ks) {
        short8 b0 = *(const short8*)(bfw + (size_t)(((bbase + ks) * 4 + ntb + 0) * 64 + lane) * 8);
        short8 b1 = *(const short8*)(bfw + (size_t)(((bbase + ks) * 4 + ntb + 1) * 64 + lane) * 8);
#pragma unroll
        for (int mt = 0; mt < 2; ++mt) {
            short8 a = *(const short8*)&As[(ks * 4 + q) * 64 + (pt0 + mt) * 16 + m];
            acc[mt][0] = __builtin_amdgcn_mfma_f32_16x16x32_bf16(a, b0, acc[mt][0], 0, 0, 0);
            acc[mt][1] = __builtin_amdgcn_mfma_f32_16x16x32_bf16(a, b1, acc[mt][1], 0, 0, 0);
        }
    }
}

// ------------------------------------------------------------------
// fused (R3 exact): 4 padded chunks (K'=640), 20-row LDS (20480 B), (256,6)
// ------------------------------------------------------------------
__global__ __launch_bounds__(256, 6) void fused_mfma(
    const float* __restrict__ wsp,
    const float* __restrict__ b_conv,
    float* __restrict__ out)
{
    __shared__ uint4 As[20 * 64];   // 20480 B

    const int bx = blockIdx.x;
    const int b  = bx & 7;          // batch -> XCD affinity
    const int t  = bx >> 3;
    const int w0 = (t & 15) * 8;
    const int h0 = ((t >> 4) & 15) * 8;
    const int tid = threadIdx.x, lane = tid & 63, wv = tid >> 6;

    const unsigned short* upb = (const unsigned short*)wsp + (size_t)b * 64 * PLN;
    const float* gw2 = wsp + GW2_F;
    const float* gf2 = wsp + GF2_F;
    const float* shp = wsp + SH_F;
    const unsigned short* bfw = (const unsigned short*)wsp + BF_U16;

    f32x4 acc[2][2];
#pragma unroll
    for (int mt = 0; mt < 2; ++mt)
#pragma unroll
        for (int j = 0; j < 2; ++j) acc[mt][j] = (f32x4){0.f, 0.f, 0.f, 0.f};

    uint2 vr[4][3];
    unsigned pk[20];

    // prologue: chunk 0 (channels wv*4 .. wv*4+3)
    chunk_loads4(wv * 4, lane, h0, w0, upb, vr);
    chunk_compute4(wv * 4, lane, vr, gw2, gf2, shp, pk);
#pragma unroll
    for (int kb = 0; kb < 5; ++kb)
        As[(5 * wv + kb) * 64 + lane] =
            (uint4){pk[4 * kb], pk[4 * kb + 1], pk[4 * kb + 2], pk[4 * kb + 3]};
    __syncthreads();

#pragma unroll
    for (int c = 0; c < 4; ++c) {
        if (c < 3) chunk_loads4((c + 1) * 16 + wv * 4, lane, h0, w0, upb, vr);
        do_mfma5(c * 5, As, bfw, wv, lane, acc);
        if (c < 3) {
            chunk_compute4((c + 1) * 16 + wv * 4, lane, vr, gw2, gf2, shp, pk);
            __syncthreads();   // all waves done reading As for chunk c
#pragma unroll
            for (int kb = 0; kb < 5; ++kb)
                As[(5 * wv + kb) * 64 + lane] =
                    (uint4){pk[4 * kb], pk[4 * kb + 1], pk[4 * kb + 2], pk[4 * kb + 3]};
            __syncthreads();   // writes visible
        }
    }

    // ================= epilogue: + bias + coord field, float4 stores =================
    const int q = lane >> 4, m = lane & 15;
    const int ntb = (wv >> 1) * 2, pt0 = (wv & 1) * 2;
    const float* co = wsp + CO_F;
#pragma unroll
    for (int mt = 0; mt < 2; ++mt)
#pragma unroll
        for (int j = 0; j < 2; ++j) {
            const int oc = (ntb + j) * 16 + m;
            const int ch = (oc & 1) ? (64 + (oc >> 1)) : (oc >> 1);
            const int row = h0 + (pt0 + mt) * 2 + (q >> 1);
            const int col = w0 + (q & 1) * 4;
            const size_t pix = (size_t)row * 128 + col;
            const float4 cv = *(const float4*)(co + (size_t)oc * 16384 + pix);
            const float bias = b_conv[oc];
            float4 st = { acc[mt][j][0] + bias + cv.x,
                          acc[mt][j][1] + bias + cv.y,
                          acc[mt][j][2] + bias + cv.z,
                          acc[mt][j][3] + bias + cv.w };
            *(float4*)(out + (size_t)(b * 128 + ch) * 16384 + pix) = st;
        }
}

// ------------------------------------------------------------------
extern "C" void kernel_launch(void* const* d_in, const int* in_sizes, int n_in,
                              void* d_out, int out_size, void* d_ws, size_t ws_size,
                              hipStream_t stream)
{
    const float* x         = (const float*)d_in[0];
    const float* w_squeeze = (const float*)d_in[1];
    const float* w_gw      = (const float*)d_in[2];
    const float* w_gf      = (const float*)d_in[3];
    const float* gamma     = (const float*)d_in[4];
    const float* beta      = (const float*)d_in[5];
    const float* mean      = (const float*)d_in[6];
    const float* var       = (const float*)d_in[7];
    const float* w_conv    = (const float*)d_in[8];
    const float* b_conv    = (const float*)d_in[9];
    float* out = (float*)d_out;
    float* ws  = (float*)d_ws;

    prep_kernel<<<256, 256, 0, stream>>>(w_squeeze, gamma, beta, mean, var,
                                         w_gw, w_gf, w_conv, ws);
    squeeze_mfma<<<4096, 256, 0, stream>>>(x, ws, out);
    fused_mfma<<<2048, 256, 0, stream>>>(ws, b_conv, out);
}